// Round 5
// baseline (332.276 us; speedup 1.0000x reference)
//
#include <hip/hip_runtime.h>
#include <hip/hip_bf16.h>
#include <math.h>

#define BB 8
#define SS 2048
#define DD 1024
#define HH 16
#define DHH 64
#define NROWS (BB*SS)   // 16384
#define QSLICE ((size_t)BB * HH * SS)   // elems per qscore K-split slice

typedef unsigned short u16;
typedef __attribute__((ext_vector_type(8))) __bf16 bf16x8;
typedef __attribute__((ext_vector_type(4))) float f32x4;
typedef __attribute__((ext_vector_type(16))) float f32x16;

__device__ __forceinline__ u16 f2bf(float f) {
    union { float f; unsigned u; } v; v.f = f;
    unsigned r = v.u + 0x7fffu + ((v.u >> 16) & 1u);
    return (u16)(r >> 16);
}
__device__ __forceinline__ float bf2f(u16 b) {
    union { unsigned u; float f; } v; v.u = ((unsigned)b) << 16;
    return v.f;
}

__device__ __forceinline__ void load_lds16(const void* g, void* l) {
    __builtin_amdgcn_global_load_lds(
        (const __attribute__((address_space(1))) unsigned int*)g,
        (__attribute__((address_space(3))) unsigned int*)l,
        16, 0, 0);
}

// ---------------- cast hs fp32 -> bf16 ----------------
__global__ __launch_bounds__(256) void cast_bf16_kernel(const float* __restrict__ in,
                                                        u16* __restrict__ out, int n4) {
    int i = blockIdx.x * 256 + threadIdx.x;
    if (i >= n4) return;
    float4 v = ((const float4*)in)[i];
    ushort4 o;
    o.x = f2bf(v.x); o.y = f2bf(v.y); o.z = f2bf(v.z); o.w = f2bf(v.w);
    ((ushort4*)out)[i] = o;
}

// ---------------- W [K,M] fp32 -> WT [M,K] bf16 ----------------
__global__ __launch_bounds__(256) void transpose_cast_kernel(const float* __restrict__ W,
                                                             u16* __restrict__ WT) {
    __shared__ float tile[32][33];
    int m0 = blockIdx.x * 32, k0 = blockIdx.y * 32;
    int tx = threadIdx.x & 31, ty = threadIdx.x >> 5;
    #pragma unroll
    for (int i = 0; i < 4; i++) {
        int kk = ty + i * 8;
        tile[kk][tx] = W[(k0 + kk) * DD + m0 + tx];
    }
    __syncthreads();
    #pragma unroll
    for (int i = 0; i < 4; i++) {
        int mm = ty + i * 8;
        WT[(m0 + mm) * DD + k0 + tx] = f2bf(tile[tx][mm]);
    }
}

// ---------------- Wqa [1024][16] fp32 -> WqaT [16][1024] bf16 ----------------
__global__ __launch_bounds__(256) void wqa_transpose_kernel(const float* __restrict__ Wqa,
                                                            u16* __restrict__ WqaT) {
    int i = blockIdx.x * 256 + threadIdx.x;
    int h = i >> 10, k = i & 1023;
    WqaT[i] = f2bf(Wqa[k * HH + h]);
}

// ---------------- shared GEMM core: 128x128 tile, BK=64, XOR-swizzled LDS ----------------
// 4 waves, each 64x64 via 2x2 of mfma_f32_32x32x16_bf16.
// LDS: row stride 64 elems (128 B); 16B chunk c of row r stored at chunk-pos c^(r&7).
__device__ __forceinline__ void gemm_core(const u16* __restrict__ A,
                                          const u16* __restrict__ BT,
                                          int row0, int col0,
                                          u16* sA, u16* sB,
                                          f32x16 acc[2][2]) {
    const int t = threadIdx.x;
    const int lane = t & 63;
    const int w = t >> 6;
    const int wr = (w >> 1) * 64, wc = (w & 1) * 64;
    const int l31 = lane & 31, khalf = lane >> 5;

    #pragma unroll
    for (int i = 0; i < 2; i++)
        #pragma unroll
        for (int j = 0; j < 2; j++)
            #pragma unroll
            for (int r = 0; r < 16; r++)
                acc[i][j][r] = 0.f;

    // staging: thread t owns LDS rows (j*32 + t>>3), chunk-position t&7,
    // which must hold global chunk (t&7) ^ ((t>>3)&7).
    const int srow = t >> 3;
    const int scol = ((t & 7) ^ (srow & 7)) * 8;
    const u16* Ag = A + (size_t)(row0 + srow) * DD + scol;
    const u16* Bg = BT + (size_t)(col0 + srow) * DD + scol;

    for (int k0 = 0; k0 < DD; k0 += 64) {
        __syncthreads();
        #pragma unroll
        for (int j = 0; j < 4; j++) {
            load_lds16(Ag + k0 + (size_t)j * 32 * DD, &sA[j * 2048 + t * 8]);
            load_lds16(Bg + k0 + (size_t)j * 32 * DD, &sB[j * 2048 + t * 8]);
        }
        __syncthreads();
        #pragma unroll
        for (int ks = 0; ks < 4; ks++) {            // K=16 per step
            const int cpos = ((ks * 2 + khalf) ^ (l31 & 7)) * 8;
            bf16x8 af[2], bfr[2];
            #pragma unroll
            for (int i = 0; i < 2; i++) {
                af[i]  = *(const bf16x8*)&sA[(wr + i * 32 + l31) * 64 + cpos];
                bfr[i] = *(const bf16x8*)&sB[(wc + i * 32 + l31) * 64 + cpos];
            }
            #pragma unroll
            for (int mi = 0; mi < 2; mi++)
                #pragma unroll
                for (int ni = 0; ni < 2; ni++)
                    acc[mi][ni] = __builtin_amdgcn_mfma_f32_32x32x16_bf16(
                        af[mi], bfr[ni], acc[mi][ni], 0, 0, 0);
        }
    }
}

// ---------------- fused Q+K gemm: y<8 -> q side, y>=8 -> k side; bf16 out ----------------
__global__ __launch_bounds__(256)
void gemm_qk_kernel(const u16* __restrict__ A,
                    const u16* __restrict__ WqT, const u16* __restrict__ WkT,
                    const float* __restrict__ bq, const float* __restrict__ bk,
                    u16* __restrict__ qb, u16* __restrict__ kb) {
    __shared__ u16 sA[128 * 64];
    __shared__ u16 sB[128 * 64];
    const int row0 = blockIdx.x * 128;
    const bool isQ = blockIdx.y < 8;
    const int col0 = (isQ ? blockIdx.y : blockIdx.y - 8) * 128;
    const u16* BT = isQ ? WqT : WkT;
    const float* bias = isQ ? bq : bk;
    u16* Cb = isQ ? qb : kb;

    f32x16 acc[2][2];
    gemm_core(A, BT, row0, col0, sA, sB, acc);

    const int lane = threadIdx.x & 63, w = threadIdx.x >> 6;
    const int wr = (w >> 1) * 64, wc = (w & 1) * 64;
    const int l31 = lane & 31, khalf = lane >> 5;
    #pragma unroll
    for (int ti = 0; ti < 2; ti++)
        #pragma unroll
        for (int tj = 0; tj < 2; tj++) {
            int col = col0 + wc + tj * 32 + l31;
            float bv = bias[col];
            #pragma unroll
            for (int r = 0; r < 16; r++) {
                int m = (r & 3) + 8 * (r >> 2) + 4 * khalf;
                int row = row0 + wr + ti * 32 + m;
                Cb[(size_t)row * DD + col] = f2bf(acc[ti][tj][r] + bv);
            }
        }
}

// ---------------- final gemm: out = q_bf @ WtTs[b]^T + bt + q_bf (residual) ----------------
__global__ __launch_bounds__(256)
void gemm_out_kernel(const u16* __restrict__ A, const u16* __restrict__ WtTs,
                     const float* __restrict__ bt, const u16* __restrict__ res,
                     float* __restrict__ out) {
    __shared__ u16 sA[128 * 64];
    __shared__ u16 sB[128 * 64];
    const int row0 = blockIdx.x * 128;
    const int col0 = blockIdx.y * 128;
    const u16* BT = WtTs + (size_t)(row0 >> 11) * DD * DD;   // per-batch scaled Wt

    f32x16 acc[2][2];
    gemm_core(A, BT, row0, col0, sA, sB, acc);

    const int lane = threadIdx.x & 63, w = threadIdx.x >> 6;
    const int wr = (w >> 1) * 64, wc = (w & 1) * 64;
    const int l31 = lane & 31, khalf = lane >> 5;
    #pragma unroll
    for (int ti = 0; ti < 2; ti++)
        #pragma unroll
        for (int tj = 0; tj < 2; tj++) {
            int col = col0 + wc + tj * 32 + l31;
            float bv = bt[col];
            #pragma unroll
            for (int r = 0; r < 16; r++) {
                int m = (r & 3) + 8 * (r >> 2) + 4 * khalf;
                int row = row0 + wr + ti * 32 + m;
                size_t idx = (size_t)row * DD + col;
                out[idx] = acc[ti][tj][r] + bv + bf2f(res[idx]);
            }
        }
}

// ---------------- raw qscore via MFMA, K-split 4 -> separate slices ----------------
// grid = (NROWS/64, 4). qraw[split][b][h][s] = sum_{k in split} q[s][k]*Wqa[k][h]
__global__ __launch_bounds__(256)
void qscore_mfma_kernel(const u16* __restrict__ qbf, const u16* __restrict__ WqaT,
                        float* __restrict__ qraw) {
    int w = threadIdx.x >> 6, lane = threadIdx.x & 63;
    int row0 = blockIdx.x * 64 + w * 16;
    int kbase = blockIdx.y * 256;
    int m16 = lane & 15, quad = lane >> 4;
    f32x4 acc = (f32x4){0.f, 0.f, 0.f, 0.f};
    const u16* ap = qbf + (size_t)(row0 + m16) * DD + kbase + quad * 8;
    const u16* bp = WqaT + (size_t)m16 * DD + kbase + quad * 8;
    #pragma unroll
    for (int kk = 0; kk < 256; kk += 32) {
        bf16x8 a = *(const bf16x8*)(ap + kk);
        bf16x8 b = *(const bf16x8*)(bp + kk);
        acc = __builtin_amdgcn_mfma_f32_16x16x32_bf16(a, b, acc, 0, 0, 0);
    }
    #pragma unroll
    for (int r = 0; r < 4; r++) {
        int grow = row0 + quad * 4 + r;
        int b = grow >> 11, sidx = grow & 2047;
        qraw[((size_t)(blockIdx.y * BB + b) * HH + m16) * SS + sidx] = acc[r];
    }
}

// ---------------- softmax over S, writes slice 0 ----------------
template<bool EPI>
__global__ __launch_bounds__(256)
void softmax_kernel(float* __restrict__ score, const float* __restrict__ bqa,
                    const float* __restrict__ mask) {
    int bh = blockIdx.x;
    int b = bh >> 4, h = bh & 15;
    float* srow = score + ((size_t)bh << 11);
    __shared__ float rm[4], rs[4];
    int t = threadIdx.x;

    float v[8];
    float m = -1e30f;
    #pragma unroll
    for (int i = 0; i < 8; i++) {
        int off = t + i * 256;
        float x;
        if (EPI) {
            x = srow[off] + srow[off + QSLICE] + srow[off + 2 * QSLICE] + srow[off + 3 * QSLICE];
            x = (x + bqa[h]) * 0.125f + mask[b * SS + off];
        } else {
            x = srow[off];
        }
        v[i] = x; m = fmaxf(m, x);
    }
    #pragma unroll
    for (int off = 32; off; off >>= 1) m = fmaxf(m, __shfl_xor(m, off));
    if ((t & 63) == 0) rm[t >> 6] = m;
    __syncthreads();
    m = fmaxf(fmaxf(rm[0], rm[1]), fmaxf(rm[2], rm[3]));

    float sum = 0.f;
    #pragma unroll
    for (int i = 0; i < 8; i++) { v[i] = __expf(v[i] - m); sum += v[i]; }
    #pragma unroll
    for (int off = 32; off; off >>= 1) sum += __shfl_xor(sum, off);
    if ((t & 63) == 0) rs[t >> 6] = sum;
    __syncthreads();
    float inv = 1.0f / (rs[0] + rs[1] + rs[2] + rs[3]);
    #pragma unroll
    for (int i = 0; i < 8; i++) srow[t + i * 256] = v[i] * inv;
}

// ---------------- pooled[b,:,:] += sum_{s in 32-chunk} w[b,h,s] * X[b,s,:] ----------------
__global__ __launch_bounds__(256)
void pool_kernel(const float* __restrict__ w, const u16* __restrict__ X,
                 float* __restrict__ pooled) {
    int b = blockIdx.x;
    int s0 = blockIdx.y * 32;
    int t = threadIdx.x;
    int wid = t >> 6, lane = t & 63;
    int h = lane >> 2;
    __shared__ float sw[16 * 33];
    __shared__ float pr[4][64 * 17];
    {
        int hh = t >> 4, si = t & 15;
        const float* wr = w + ((size_t)(b * HH + hh) << 11) + s0;
        sw[hh * 33 + si] = wr[si];
        sw[hh * 33 + si + 16] = wr[si + 16];
    }
    __syncthreads();
    float acc[16];
    #pragma unroll
    for (int j = 0; j < 16; j++) acc[j] = 0.f;
    const u16* xbase = X + ((size_t)(b * SS + s0 + wid * 8) << 10) + lane * 16;
    #pragma unroll
    for (int rr = 0; rr < 8; rr++) {
        float ws = sw[h * 33 + wid * 8 + rr];
        const uint4* xp = (const uint4*)(xbase + (size_t)rr * DD);
        uint4 x0 = xp[0], x1 = xp[1];
        unsigned xw[8] = {x0.x, x0.y, x0.z, x0.w, x1.x, x1.y, x1.z, x1.w};
        #pragma unroll
        for (int i2 = 0; i2 < 8; i2++) {
            union { unsigned u; float f; } lo, hi;
            lo.u = xw[i2] << 16; hi.u = xw[i2] & 0xffff0000u;
            acc[2 * i2]     += ws * lo.f;
            acc[2 * i2 + 1] += ws * hi.f;
        }
    }
    #pragma unroll
    for (int j = 0; j < 16; j++) pr[wid][lane * 17 + j] = acc[j];
    __syncthreads();
    #pragma unroll
    for (int i = 0; i < 4; i++) {
        int idx = t + i * 256;
        int l2 = idx >> 4, j2 = idx & 15;
        float v = pr[0][l2 * 17 + j2] + pr[1][l2 * 17 + j2] +
                  pr[2][l2 * 17 + j2] + pr[3][l2 * 17 + j2];
        int od = (l2 >> 2) * 64 + (l2 & 3) * 16 + j2;
        atomicAdd(&pooled[b * DD + od], v);
    }
}

// ---------------- qk_score[b,h,s] = (k[b,s,h*64:]·pq[b,h,:])*scale + mask ----------------
__global__ __launch_bounds__(256)
void qkscore_kernel(const u16* __restrict__ kbf, const float* __restrict__ pq,
                    const float* __restrict__ mask, float* __restrict__ qkscore) {
    int row = blockIdx.x * 4 + (threadIdx.x >> 6);
    int lane = threadIdx.x & 63;
    int b = row >> 11, s = row & 2047;
    int h = lane >> 2, dp = lane & 3;
    const u16* kp = kbf + (size_t)row * DD + h * 64 + dp * 16;
    const float* pqp = pq + (size_t)(b * HH + h) * 64 + dp * 16;
    const uint4* kp4 = (const uint4*)kp;
    uint4 ka = kp4[0], kb4 = kp4[1];
    unsigned kw[8] = {ka.x, ka.y, ka.z, ka.w, kb4.x, kb4.y, kb4.z, kb4.w};
    float acc = 0.f;
    #pragma unroll
    for (int i = 0; i < 8; i++) {
        union { unsigned u; float f; } lo, hi;
        lo.u = kw[i] << 16;
        hi.u = kw[i] & 0xffff0000u;
        acc += lo.f * pqp[2 * i] + hi.f * pqp[2 * i + 1];
    }
    acc += __shfl_xor(acc, 1);
    acc += __shfl_xor(acc, 2);
    if (dp == 0) qkscore[(size_t)(b * HH + h) * SS + s] = acc * 0.125f + mask[b * SS + s];
}

// ---------------- WtTs[b][m][k] = WtT[m][k] * pk[b][k] ----------------
__global__ __launch_bounds__(256)
void scale_wt_kernel(const u16* __restrict__ WtT, const float* __restrict__ pk,
                     u16* __restrict__ WtTs) {
    int i = blockIdx.x * 256 + threadIdx.x;     // ushort4 index over [8][1024][256]
    int b = i >> 18;
    int m = (i >> 8) & 1023;
    int k4 = (i & 255) << 2;
    ushort4 wv = ((const ushort4*)WtT)[(m << 8) + (i & 255)];
    const float4 p = *(const float4*)(pk + b * DD + k4);
    ushort4 o;
    o.x = f2bf(bf2f(wv.x) * p.x); o.y = f2bf(bf2f(wv.y) * p.y);
    o.z = f2bf(bf2f(wv.z) * p.z); o.w = f2bf(bf2f(wv.w) * p.w);
    ((ushort4*)WtTs)[i] = o;
}

extern "C" void kernel_launch(void* const* d_in, const int* in_sizes, int n_in,
                              void* d_out, int out_size, void* d_ws, size_t ws_size,
                              hipStream_t stream) {
    const float* hs   = (const float*)d_in[0];
    const float* mask = (const float*)d_in[1];
    const float* Wq   = (const float*)d_in[2];
    const float* bq   = (const float*)d_in[3];
    const float* Wqa  = (const float*)d_in[4];
    const float* bqa  = (const float*)d_in[5];
    const float* Wk   = (const float*)d_in[6];
    const float* bk   = (const float*)d_in[7];
    const float* Wt   = (const float*)d_in[8];
    const float* bt   = (const float*)d_in[9];
    float* out = (float*)d_out;

    char* ws = (char*)d_ws;
    u16*   hs_bf = (u16*)ws;   ws += (size_t)NROWS * DD * 2;
    u16*   WqT   = (u16*)ws;   ws += (size_t)DD * DD * 2;
    u16*   WkT   = (u16*)ws;   ws += (size_t)DD * DD * 2;
    u16*   WtT   = (u16*)ws;   ws += (size_t)DD * DD * 2;
    u16*   WqaT  = (u16*)ws;   ws += (size_t)HH * DD * 2;
    u16*   q_bf  = (u16*)ws;   ws += (size_t)NROWS * DD * 2;
    u16*   k_bf  = (u16*)ws;   ws += (size_t)NROWS * DD * 2;
    float* qraw  = (float*)ws; ws += QSLICE * 4 * 4;   // 4 K-split slices
    float* qksc  = (float*)ws; ws += (size_t)BB * HH * SS * 4;
    float* pq    = (float*)ws; ws += (size_t)BB * DD * 4;
    float* pk    = (float*)ws; ws += (size_t)BB * DD * 4;
    u16*   WtTs  = (u16*)ws;   ws += (size_t)BB * DD * DD * 2;

    int n4 = NROWS * DD / 4;
    cast_bf16_kernel<<<n4 / 256, 256, 0, stream>>>(hs, hs_bf, n4);
    transpose_cast_kernel<<<dim3(32, 32), 256, 0, stream>>>(Wq, WqT);
    transpose_cast_kernel<<<dim3(32, 32), 256, 0, stream>>>(Wk, WkT);
    transpose_cast_kernel<<<dim3(32, 32), 256, 0, stream>>>(Wt, WtT);
    wqa_transpose_kernel<<<HH * DD / 256, 256, 0, stream>>>(Wqa, WqaT);

    hipMemsetAsync(pq, 0, (size_t)BB * DD * 4, stream);
    hipMemsetAsync(pk, 0, (size_t)BB * DD * 4, stream);

    gemm_qk_kernel<<<dim3(NROWS / 128, 16), 256, 0, stream>>>(hs_bf, WqT, WkT, bq, bk, q_bf, k_bf);

    qscore_mfma_kernel<<<dim3(NROWS / 64, 4), 256, 0, stream>>>(q_bf, WqaT, qraw);
    softmax_kernel<true><<<BB * HH, 256, 0, stream>>>(qraw, bqa, mask);
    pool_kernel<<<dim3(BB, SS / 32), 256, 0, stream>>>(qraw, q_bf, pq);
    qkscore_kernel<<<NROWS / 4, 256, 0, stream>>>(k_bf, pq, mask, qksc);
    softmax_kernel<false><<<BB * HH, 256, 0, stream>>>(qksc, nullptr, nullptr);
    pool_kernel<<<dim3(BB, SS / 32), 256, 0, stream>>>(qksc, k_bf, pk);

    scale_wt_kernel<<<(BB * DD * DD / 4) / 256, 256, 0, stream>>>(WtT, pk, WtTs);
    gemm_out_kernel<<<dim3(NROWS / 128, DD / 128), 256, 0, stream>>>(q_bf, WtTs, bt, q_bf, out);
}